// Round 3
// baseline (70.973 us; speedup 1.0000x reference)
//
#include <hip/hip_runtime.h>

// PQC: h = tanh(x @ W^T) * scale; 8-qubit circuit via exact transfer-matrix
// contraction (CNOT staircase => MPS bond dim 2; <Z_i> = 1D chain contraction
// with symmetry-reduced 2x3 state). Fully wave-local: no LDS, no syncthreads.
// Wave = 16 samples. GEMM: lane = (s4 = sample subgroup)<<4 | (c16 = col group).
// After butterfly reduce, every lane owns one sample (4x redundant) and runs
// the circuit thread-locally; 16 representative lanes store.

__device__ __forceinline__ float fast_tanh(float v) {
    float e = __expf(2.0f * v);
    return 1.0f - 2.0f / (e + 1.0f);   // exact at +/-inf overflow
}

__global__ __launch_bounds__(256, 4)
void pqc_kernel(const float* __restrict__ x,
                const float* __restrict__ Wp,
                const float* __restrict__ scalep,
                const float* __restrict__ wts,
                float* __restrict__ out)
{
    const int tid   = threadIdx.x;
    const int lane  = tid & 63;
    const int wave  = tid >> 6;                 // 0..3
    const int rbase = blockIdx.x * 64 + wave * 16;

    const int s4  = lane >> 4;                  // 0..3 sample subgroup (rows s4*4..s4*4+3)
    const int c16 = lane & 15;                  // 0..15 column group

    // ---------------- projection: 16 samples per wave, prefetched ----------------
    const float* xrow = x + (size_t)(rbase + s4 * 4) * 768 + c16 * 4;

    float acc[4][8];
    #pragma unroll
    for (int p = 0; p < 4; ++p)
        #pragma unroll
        for (int q = 0; q < 8; ++q) acc[p][q] = 0.0f;

    float4 xv[4], xn[4];
    #pragma unroll
    for (int p = 0; p < 4; ++p)
        xv[p] = *reinterpret_cast<const float4*>(xrow + p * 768);

    #pragma unroll 1
    for (int j = 0; j < 12; ++j) {
        // W loads first (L1/L2-resident, 24 KB) ...
        float4 wv[8];
        const float* wcol = Wp + j * 64 + c16 * 4;
        #pragma unroll
        for (int q = 0; q < 8; ++q)
            wv[q] = *reinterpret_cast<const float4*>(wcol + q * 768);
        // ... then next x tile, so FMAs wait at vmcnt(4) with x still in flight
        if (j < 11) {
            const float* xcol = xrow + (j + 1) * 64;
            #pragma unroll
            for (int p = 0; p < 4; ++p)
                xn[p] = *reinterpret_cast<const float4*>(xcol + p * 768);
        }
        #pragma unroll
        for (int p = 0; p < 4; ++p)
            #pragma unroll
            for (int q = 0; q < 8; ++q) {
                acc[p][q] = fmaf(xv[p].x, wv[q].x, acc[p][q]);
                acc[p][q] = fmaf(xv[p].y, wv[q].y, acc[p][q]);
                acc[p][q] = fmaf(xv[p].z, wv[q].z, acc[p][q]);
                acc[p][q] = fmaf(xv[p].w, wv[q].w, acc[p][q]);
            }
        #pragma unroll
        for (int p = 0; p < 4; ++p) xv[p] = xn[p];
    }

    // butterfly reduce over the 16 column lanes (bits 0..3 only)
    #pragma unroll
    for (int m = 1; m <= 8; m <<= 1)
        #pragma unroll
        for (int p = 0; p < 4; ++p)
            #pragma unroll
            for (int q = 0; q < 8; ++q)
                acc[p][q] += __shfl_xor(acc[p][q], m, 64);

    // each lane selects its own sample: p_sel = lane&3 (3 cndmasks per q)
    const bool b0 = (lane & 1) != 0;
    const bool b1 = (lane & 2) != 0;
    float h[8];
    #pragma unroll
    for (int q = 0; q < 8; ++q) {
        const float v01 = b0 ? acc[1][q] : acc[0][q];
        const float v23 = b0 ? acc[3][q] : acc[2][q];
        h[q] = b1 ? v23 : v01;
    }
    const int samp = rbase + s4 * 4 + (lane & 3);

    // ---------------- per-sample angles ----------------
    const float scl = scalep[0];
    float f0[8], f1[8];
    #pragma unroll
    for (int q = 0; q < 8; ++q) {
        float ang = fast_tanh(h[q]) * scl + wts[q];   // fold layer-0 weight RY
        __sincosf(0.5f * ang, &f1[q], &f0[q]);
    }
    float c2[8], s2[8], cs[8];
    #pragma unroll
    for (int q = 0; q < 8; ++q) {
        float sw, cw;
        __sincosf(0.5f * wts[8 + q], &sw, &cw);
        c2[q] = cw * cw; s2[q] = sw * sw; cs[q] = cw * sw;
    }

    // ---------------- transfer-matrix contraction (thread-local) ----------------
    // state over (b, sym(beta,beta~)): [2][3]; prefix sweep Lp[q] = L^(q)
    float Lp[9][2][3];
    Lp[0][0][0] = 1.f; Lp[0][0][1] = 0.f; Lp[0][0][2] = 0.f;
    Lp[0][1][0] = 0.f; Lp[0][1][1] = 0.f; Lp[0][1][2] = 0.f;

    #pragma unroll
    for (int q = 0; q < 8; ++q) {
        const float A = f0[q] * f0[q];
        const float B = f0[q] * f1[q];
        const float C = f1[q] * f1[q];
        float u[2][3];
        #pragma unroll
        for (int b = 0; b < 2; ++b) {
            const float v0 = Lp[q][b][0], v1 = Lp[q][b][1], v2 = Lp[q][b][2];
            u[b][0] = A * v0 + 2.f * B * v1 + C * v2;
            u[b][1] = B * v0 + (A + C) * v1 + B * v2;
            u[b][2] = C * v0 + 2.f * B * v1 + A * v2;
        }
        Lp[q+1][0][0] = c2[q] * u[0][0] + s2[q] * u[1][0];
        Lp[q+1][1][0] = s2[q] * u[0][0] + c2[q] * u[1][0];
        const float m = cs[q] * (u[1][1] - u[0][1]);
        Lp[q+1][0][1] = m;
        Lp[q+1][1][1] = -m;
        Lp[q+1][0][2] = s2[q] * u[0][2] + c2[q] * u[1][2];
        Lp[q+1][1][2] = c2[q] * u[0][2] + s2[q] * u[1][2];
    }

    // suffix sweep + signed dots
    float S[2][3] = {{1.f, 1.f, 1.f}, {1.f, 1.f, 1.f}};
    float z[8];
    #pragma unroll
    for (int i = 7; i >= 0; --i) {
        z[i] = (S[0][0] * Lp[i+1][0][0] + 2.f * S[0][1] * Lp[i+1][0][1] + S[0][2] * Lp[i+1][0][2])
             - (S[1][0] * Lp[i+1][1][0] + 2.f * S[1][1] * Lp[i+1][1][1] + S[1][2] * Lp[i+1][1][2]);
        if (i > 0) {
            float u[2][3];
            u[0][0] = c2[i] * S[0][0] + s2[i] * S[1][0];
            u[1][0] = s2[i] * S[0][0] + c2[i] * S[1][0];
            const float m = cs[i] * (S[1][1] - S[0][1]);
            u[0][1] = m; u[1][1] = -m;
            u[0][2] = s2[i] * S[0][2] + c2[i] * S[1][2];
            u[1][2] = c2[i] * S[0][2] + s2[i] * S[1][2];
            const float A = f0[i] * f0[i];
            const float B = f0[i] * f1[i];
            const float C = f1[i] * f1[i];
            #pragma unroll
            for (int b = 0; b < 2; ++b) {
                const float u0 = u[b][0], u1 = u[b][1], u2 = u[b][2];
                S[b][0] = A * u0 + 2.f * B * u1 + C * u2;
                S[b][1] = B * u0 + (A + C) * u1 + B * u2;
                S[b][2] = C * u0 + 2.f * B * u1 + A * u2;
            }
        }
    }

    // one representative lane per sample stores (lanes 0-3,16-19,32-35,48-51)
    if ((lane & 12) == 0) {
        float4* o = reinterpret_cast<float4*>(out + (size_t)samp * 8);
        o[0] = make_float4(z[0], z[1], z[2], z[3]);
        o[1] = make_float4(z[4], z[5], z[6], z[7]);
    }
}

extern "C" void kernel_launch(void* const* d_in, const int* in_sizes, int n_in,
                              void* d_out, int out_size, void* d_ws, size_t ws_size,
                              hipStream_t stream) {
    const float* x   = (const float*)d_in[0];
    const float* W   = (const float*)d_in[1];
    const float* sc  = (const float*)d_in[2];
    const float* wt  = (const float*)d_in[3];
    float* o         = (float*)d_out;

    const int batch  = in_sizes[0] / 768;     // 65536
    const int blocks = batch / 64;            // 64 samples per block
    pqc_kernel<<<dim3(blocks), dim3(256), 0, stream>>>(x, W, sc, wt, o);
}

// Round 4
// 53.845 us; speedup vs baseline: 1.3181x; 1.3181x over previous
//
#include <hip/hip_runtime.h>

// PQC: h = tanh(x @ W^T) * scale; 8-qubit circuit via exact transfer-matrix
// contraction (CNOT staircase => MPS bond dim 2; symmetry-reduced 2x3 state).
// Wave-local (no LDS/syncthreads). Circuit uses midpoint-checkpointed
// forward/backward sweeps so peak live state ~66 floats -> no spills.
// amdgpu_waves_per_eu(4,4) pins the VGPR budget at 128 (grid = 4 waves/EU).

__device__ __forceinline__ float fast_tanh(float v) {
    float e = __expf(2.0f * v);
    return 1.0f - 2.0f / (e + 1.0f);   // exact at +/-inf overflow
}

// forward site step: data/layer0-RY conjugation M(A,B,1-A), then layer1-RY+CNOT mix
__device__ __forceinline__ void fwd_step(float (&L)[2][3], float A, float B,
                                         float c2, float cs) {
    float u[2][3];
    #pragma unroll
    for (int b = 0; b < 2; ++b) {
        const float v0 = L[b][0], v1 = L[b][1], v2 = L[b][2];
        const float d  = v0 - v2;
        const float B2 = B + B;
        u[b][0] = fmaf(A, d, fmaf(B2, v1, v2));      // A v0 + 2B v1 + (1-A) v2
        u[b][1] = fmaf(B, v0 + v2, v1);              // B v0 + v1 + B v2
        u[b][2] = fmaf(-A, d, fmaf(B2, v1, v0));     // (1-A) v0 + 2B v1 + A v2
    }
    const float d0 = u[0][0] - u[1][0];
    L[0][0] = fmaf(c2, d0, u[1][0]);                 // c2 u00 + (1-c2) u10
    L[1][0] = fmaf(-c2, d0, u[0][0]);                // (1-c2) u00 + c2 u10
    const float m = cs * (u[1][1] - u[0][1]);
    L[0][1] = m;  L[1][1] = -m;
    const float d2 = u[1][2] - u[0][2];
    L[0][2] = fmaf(c2, d2, u[0][2]);                 // (1-c2) u02 + c2 u12
    L[1][2] = fmaf(-c2, d2, u[1][2]);                // c2 u02 + (1-c2) u12
}

// backward site step: mix first, then M (adjoint under (1,2,1) weighting)
__device__ __forceinline__ void bwd_step(float (&S)[2][3], float A, float B,
                                         float c2, float cs) {
    float u[2][3];
    const float d0 = S[0][0] - S[1][0];
    u[0][0] = fmaf(c2, d0, S[1][0]);
    u[1][0] = fmaf(-c2, d0, S[0][0]);
    const float m = cs * (S[1][1] - S[0][1]);
    u[0][1] = m;  u[1][1] = -m;
    const float d2 = S[1][2] - S[0][2];
    u[0][2] = fmaf(c2, d2, S[0][2]);
    u[1][2] = fmaf(-c2, d2, S[1][2]);
    #pragma unroll
    for (int b = 0; b < 2; ++b) {
        const float v0 = u[b][0], v1 = u[b][1], v2 = u[b][2];
        const float d  = v0 - v2;
        const float B2 = B + B;
        S[b][0] = fmaf(A, d, fmaf(B2, v1, v2));
        S[b][1] = fmaf(B, v0 + v2, v1);
        S[b][2] = fmaf(-A, d, fmaf(B2, v1, v0));
    }
}

__device__ __forceinline__ float zdot(const float (&S)[2][3], const float (&L)[2][3]) {
    return (S[0][0]*L[0][0] + 2.f*S[0][1]*L[0][1] + S[0][2]*L[0][2])
         - (S[1][0]*L[1][0] + 2.f*S[1][1]*L[1][1] + S[1][2]*L[1][2]);
}

__global__ __launch_bounds__(256)
__attribute__((amdgpu_waves_per_eu(4, 4)))
void pqc_kernel(const float* __restrict__ x,
                const float* __restrict__ Wp,
                const float* __restrict__ scalep,
                const float* __restrict__ wts,
                float* __restrict__ out)
{
    const int tid   = threadIdx.x;
    const int lane  = tid & 63;
    const int wave  = tid >> 6;
    const int rbase = blockIdx.x * 64 + wave * 16;

    const int s4  = lane >> 4;      // sample subgroup: rows s4*4 .. s4*4+3
    const int c16 = lane & 15;      // column group

    // ---------------- projection: 16 samples per wave ----------------
    const float* xrow = x + (size_t)(rbase + s4 * 4) * 768 + c16 * 4;

    float acc[4][8];
    #pragma unroll
    for (int p = 0; p < 4; ++p)
        #pragma unroll
        for (int q = 0; q < 8; ++q) acc[p][q] = 0.0f;

    #pragma unroll 1
    for (int j = 0; j < 12; ++j) {
        float4 wv[8];
        const float* wcol = Wp + j * 64 + c16 * 4;
        #pragma unroll
        for (int q = 0; q < 8; ++q)
            wv[q] = *reinterpret_cast<const float4*>(wcol + q * 768);
        float4 xv[4];
        #pragma unroll
        for (int p = 0; p < 4; ++p)
            xv[p] = *reinterpret_cast<const float4*>(xrow + j * 64 + p * 768);
        #pragma unroll
        for (int p = 0; p < 4; ++p)
            #pragma unroll
            for (int q = 0; q < 8; ++q) {
                acc[p][q] = fmaf(xv[p].x, wv[q].x, acc[p][q]);
                acc[p][q] = fmaf(xv[p].y, wv[q].y, acc[p][q]);
                acc[p][q] = fmaf(xv[p].z, wv[q].z, acc[p][q]);
                acc[p][q] = fmaf(xv[p].w, wv[q].w, acc[p][q]);
            }
    }

    // butterfly reduce over the 16 column lanes
    #pragma unroll
    for (int m = 1; m <= 8; m <<= 1)
        #pragma unroll
        for (int p = 0; p < 4; ++p)
            #pragma unroll
            for (int q = 0; q < 8; ++q)
                acc[p][q] += __shfl_xor(acc[p][q], m, 64);

    // every lane selects one sample (4x redundant circuit, no divergence)
    const bool bb0 = (lane & 1) != 0;
    const bool bb1 = (lane & 2) != 0;
    float h[8];
    #pragma unroll
    for (int q = 0; q < 8; ++q) {
        const float v01 = bb0 ? acc[1][q] : acc[0][q];
        const float v23 = bb0 ? acc[3][q] : acc[2][q];
        h[q] = bb1 ? v23 : v01;
    }
    const int samp = rbase + s4 * 4 + (lane & 3);

    // ---------------- per-site tables ----------------
    const float scl = scalep[0];
    float Aq[8], Bq[8], c2q[8], csq[8];
    #pragma unroll
    for (int q = 0; q < 8; ++q) {
        float ang = fast_tanh(h[q]) * scl + wts[q];   // fold layer-0 weight RY
        float s, c;
        __sincosf(0.5f * ang, &s, &c);
        Aq[q] = c * c;  Bq[q] = c * s;
        float sw, cw;
        __sincosf(0.5f * wts[8 + q], &sw, &cw);
        c2q[q] = cw * cw;  csq[q] = cw * sw;
    }

#define FWDQ(T, qq) fwd_step(T, Aq[qq], Bq[qq], c2q[qq], csq[qq])
#define BWDQ(qq)    bwd_step(S, Aq[qq], Bq[qq], c2q[qq], csq[qq])

    // ---------------- forward sweep with midpoint checkpoint ----------------
    float L[2][3] = {{1.f, 0.f, 0.f}, {0.f, 0.f, 0.f}};
    float K[2][3];                                    // checkpoint L_4
    #pragma unroll
    for (int q = 0; q < 8; ++q) {
        FWDQ(L, q);
        if (q == 3) {
            #pragma unroll
            for (int b = 0; b < 2; ++b)
                #pragma unroll
                for (int t = 0; t < 3; ++t) K[b][t] = L[b][t];
        }
    }

    // ---------------- backward sweep with recompute ----------------
    float S[2][3] = {{1.f, 1.f, 1.f}, {1.f, 1.f, 1.f}};
    float z[8];
    float T[2][3];

    z[7] = zdot(S, L);   BWDQ(7);                              // L = L_8

    #pragma unroll
    for (int b = 0; b < 2; ++b) { T[b][0]=K[b][0]; T[b][1]=K[b][1]; T[b][2]=K[b][2]; }
    FWDQ(T, 4); FWDQ(T, 5); FWDQ(T, 6);
    z[6] = zdot(S, T);   BWDQ(6);

    #pragma unroll
    for (int b = 0; b < 2; ++b) { T[b][0]=K[b][0]; T[b][1]=K[b][1]; T[b][2]=K[b][2]; }
    FWDQ(T, 4); FWDQ(T, 5);
    z[5] = zdot(S, T);   BWDQ(5);

    #pragma unroll
    for (int b = 0; b < 2; ++b) { T[b][0]=K[b][0]; T[b][1]=K[b][1]; T[b][2]=K[b][2]; }
    FWDQ(T, 4);
    z[4] = zdot(S, T);   BWDQ(4);

    z[3] = zdot(S, K);   BWDQ(3);                              // L_4 = K

    T[0][0]=1.f; T[0][1]=0.f; T[0][2]=0.f; T[1][0]=0.f; T[1][1]=0.f; T[1][2]=0.f;
    FWDQ(T, 0); FWDQ(T, 1); FWDQ(T, 2);
    z[2] = zdot(S, T);   BWDQ(2);

    T[0][0]=1.f; T[0][1]=0.f; T[0][2]=0.f; T[1][0]=0.f; T[1][1]=0.f; T[1][2]=0.f;
    FWDQ(T, 0); FWDQ(T, 1);
    z[1] = zdot(S, T);   BWDQ(1);

    T[0][0]=1.f; T[0][1]=0.f; T[0][2]=0.f; T[1][0]=0.f; T[1][1]=0.f; T[1][2]=0.f;
    FWDQ(T, 0);
    z[0] = zdot(S, T);

#undef FWDQ
#undef BWDQ

    // one representative lane per sample stores (lanes 0-3,16-19,32-35,48-51)
    if ((lane & 12) == 0) {
        float4* o = reinterpret_cast<float4*>(out + (size_t)samp * 8);
        o[0] = make_float4(z[0], z[1], z[2], z[3]);
        o[1] = make_float4(z[4], z[5], z[6], z[7]);
    }
}

extern "C" void kernel_launch(void* const* d_in, const int* in_sizes, int n_in,
                              void* d_out, int out_size, void* d_ws, size_t ws_size,
                              hipStream_t stream) {
    const float* x   = (const float*)d_in[0];
    const float* W   = (const float*)d_in[1];
    const float* sc  = (const float*)d_in[2];
    const float* wt  = (const float*)d_in[3];
    float* o         = (float*)d_out;

    const int batch  = in_sizes[0] / 768;     // 65536
    const int blocks = batch / 64;            // 64 samples per block
    pqc_kernel<<<dim3(blocks), dim3(256), 0, stream>>>(x, W, sc, wt, o);
}

// Round 5
// 52.800 us; speedup vs baseline: 1.3442x; 1.0198x over previous
//
#include <hip/hip_runtime.h>

// PQC: h = tanh(x @ W^T) * scale; 8-qubit circuit via exact transfer-matrix
// contraction (CNOT staircase => MPS bond dim 2; symmetry-reduced 2x3 state).
// W staged in LDS (24 KB) so the L1 path serves only streaming x; GEMM j-loop
// runs a 2-deep x prefetch (vmcnt never drains in the loop). Circuit is
// midpoint-checkpointed (no spills) and runs redundantly on all 64 lanes.

__device__ __forceinline__ float fast_tanh(float v) {
    float e = __expf(2.0f * v);
    return 1.0f - 2.0f / (e + 1.0f);   // exact at +/-inf overflow
}

// forward site step: data/layer0-RY conjugation M(A,B,1-A), then layer1-RY+CNOT mix
__device__ __forceinline__ void fwd_step(float (&L)[2][3], float A, float B,
                                         float c2, float cs) {
    float u[2][3];
    #pragma unroll
    for (int b = 0; b < 2; ++b) {
        const float v0 = L[b][0], v1 = L[b][1], v2 = L[b][2];
        const float d  = v0 - v2;
        const float B2 = B + B;
        u[b][0] = fmaf(A, d, fmaf(B2, v1, v2));      // A v0 + 2B v1 + (1-A) v2
        u[b][1] = fmaf(B, v0 + v2, v1);              // B v0 + v1 + B v2
        u[b][2] = fmaf(-A, d, fmaf(B2, v1, v0));     // (1-A) v0 + 2B v1 + A v2
    }
    const float d0 = u[0][0] - u[1][0];
    L[0][0] = fmaf(c2, d0, u[1][0]);
    L[1][0] = fmaf(-c2, d0, u[0][0]);
    const float m = cs * (u[1][1] - u[0][1]);
    L[0][1] = m;  L[1][1] = -m;
    const float d2 = u[1][2] - u[0][2];
    L[0][2] = fmaf(c2, d2, u[0][2]);
    L[1][2] = fmaf(-c2, d2, u[1][2]);
}

// backward site step: mix first, then M (adjoint under (1,2,1) weighting)
__device__ __forceinline__ void bwd_step(float (&S)[2][3], float A, float B,
                                         float c2, float cs) {
    float u[2][3];
    const float d0 = S[0][0] - S[1][0];
    u[0][0] = fmaf(c2, d0, S[1][0]);
    u[1][0] = fmaf(-c2, d0, S[0][0]);
    const float m = cs * (S[1][1] - S[0][1]);
    u[0][1] = m;  u[1][1] = -m;
    const float d2 = S[1][2] - S[0][2];
    u[0][2] = fmaf(c2, d2, S[0][2]);
    u[1][2] = fmaf(-c2, d2, S[1][2]);
    #pragma unroll
    for (int b = 0; b < 2; ++b) {
        const float v0 = u[b][0], v1 = u[b][1], v2 = u[b][2];
        const float d  = v0 - v2;
        const float B2 = B + B;
        S[b][0] = fmaf(A, d, fmaf(B2, v1, v2));
        S[b][1] = fmaf(B, v0 + v2, v1);
        S[b][2] = fmaf(-A, d, fmaf(B2, v1, v0));
    }
}

__device__ __forceinline__ float zdot(const float (&S)[2][3], const float (&L)[2][3]) {
    return (S[0][0]*L[0][0] + 2.f*S[0][1]*L[0][1] + S[0][2]*L[0][2])
         - (S[1][0]*L[1][0] + 2.f*S[1][1]*L[1][1] + S[1][2]*L[1][2]);
}

__global__ __launch_bounds__(256)
__attribute__((amdgpu_waves_per_eu(4)))
void pqc_kernel(const float* __restrict__ x,
                const float* __restrict__ Wp,
                const float* __restrict__ scalep,
                const float* __restrict__ wts,
                float* __restrict__ out)
{
    __shared__ float Wl[6144];   // 8 x 768 row-major, 24 KB

    const int tid   = threadIdx.x;
    const int lane  = tid & 63;
    const int wave  = tid >> 6;
    const int rbase = blockIdx.x * 64 + wave * 16;

    // ---- stage W into LDS (256 threads x 6 float4) ----
    {
        const float4* Wv4 = reinterpret_cast<const float4*>(Wp);
        float4*       Lv4 = reinterpret_cast<float4*>(Wl);
        #pragma unroll
        for (int k = 0; k < 6; ++k)
            Lv4[tid + k * 256] = Wv4[tid + k * 256];
    }
    __syncthreads();

    const int s4  = lane >> 4;      // sample subgroup: rows s4*4 .. s4*4+3
    const int c16 = lane & 15;      // column group

    // ---------------- projection: 16 samples per wave, 2-deep x prefetch ----
    const float* xrow = x + (size_t)(rbase + s4 * 4) * 768 + c16 * 4;

    float acc[4][8];
    #pragma unroll
    for (int p = 0; p < 4; ++p)
        #pragma unroll
        for (int q = 0; q < 8; ++q) acc[p][q] = 0.0f;

    float4 xv[4], xn[4];
    #pragma unroll
    for (int p = 0; p < 4; ++p)
        xv[p] = *reinterpret_cast<const float4*>(xrow + p * 768);

    #pragma unroll 1
    for (int j = 0; j < 12; ++j) {
        // issue next x tile first — stays in flight through this iter's FMAs
        if (j < 11) {
            const float* xcol = xrow + (j + 1) * 64;
            #pragma unroll
            for (int p = 0; p < 4; ++p)
                xn[p] = *reinterpret_cast<const float4*>(xcol + p * 768);
        }
        // W from LDS (2-way bank aliasing = free)
        float4 wv[8];
        const float* wcol = Wl + j * 64 + c16 * 4;
        #pragma unroll
        for (int q = 0; q < 8; ++q)
            wv[q] = *reinterpret_cast<const float4*>(wcol + q * 768);
        #pragma unroll
        for (int p = 0; p < 4; ++p)
            #pragma unroll
            for (int q = 0; q < 8; ++q) {
                acc[p][q] = fmaf(xv[p].x, wv[q].x, acc[p][q]);
                acc[p][q] = fmaf(xv[p].y, wv[q].y, acc[p][q]);
                acc[p][q] = fmaf(xv[p].z, wv[q].z, acc[p][q]);
                acc[p][q] = fmaf(xv[p].w, wv[q].w, acc[p][q]);
            }
        #pragma unroll
        for (int p = 0; p < 4; ++p) xv[p] = xn[p];
    }

    // butterfly reduce over the 16 column lanes
    #pragma unroll
    for (int m = 1; m <= 8; m <<= 1)
        #pragma unroll
        for (int p = 0; p < 4; ++p)
            #pragma unroll
            for (int q = 0; q < 8; ++q)
                acc[p][q] += __shfl_xor(acc[p][q], m, 64);

    // every lane selects one sample (4x redundant circuit, no divergence)
    const bool bb0 = (lane & 1) != 0;
    const bool bb1 = (lane & 2) != 0;
    float h[8];
    #pragma unroll
    for (int q = 0; q < 8; ++q) {
        const float v01 = bb0 ? acc[1][q] : acc[0][q];
        const float v23 = bb0 ? acc[3][q] : acc[2][q];
        h[q] = bb1 ? v23 : v01;
    }
    const int samp = rbase + s4 * 4 + (lane & 3);

    // ---------------- per-site tables ----------------
    const float scl = scalep[0];
    float Aq[8], Bq[8], c2q[8], csq[8];
    #pragma unroll
    for (int q = 0; q < 8; ++q) {
        float ang = fast_tanh(h[q]) * scl + wts[q];   // fold layer-0 weight RY
        float s, c;
        __sincosf(0.5f * ang, &s, &c);
        Aq[q] = c * c;  Bq[q] = c * s;
        float sw, cw;
        __sincosf(0.5f * wts[8 + q], &sw, &cw);
        c2q[q] = cw * cw;  csq[q] = cw * sw;
    }

#define FWDQ(T, qq) fwd_step(T, Aq[qq], Bq[qq], c2q[qq], csq[qq])
#define BWDQ(qq)    bwd_step(S, Aq[qq], Bq[qq], c2q[qq], csq[qq])

    // ---------------- forward sweep with midpoint checkpoint ----------------
    float L[2][3] = {{1.f, 0.f, 0.f}, {0.f, 0.f, 0.f}};
    float K[2][3];                                    // checkpoint L_4
    #pragma unroll
    for (int q = 0; q < 8; ++q) {
        FWDQ(L, q);
        if (q == 3) {
            #pragma unroll
            for (int b = 0; b < 2; ++b)
                #pragma unroll
                for (int t = 0; t < 3; ++t) K[b][t] = L[b][t];
        }
    }

    // ---------------- backward sweep with recompute ----------------
    float S[2][3] = {{1.f, 1.f, 1.f}, {1.f, 1.f, 1.f}};
    float z[8];
    float T[2][3];

    z[7] = zdot(S, L);   BWDQ(7);

    #pragma unroll
    for (int b = 0; b < 2; ++b) { T[b][0]=K[b][0]; T[b][1]=K[b][1]; T[b][2]=K[b][2]; }
    FWDQ(T, 4); FWDQ(T, 5); FWDQ(T, 6);
    z[6] = zdot(S, T);   BWDQ(6);

    #pragma unroll
    for (int b = 0; b < 2; ++b) { T[b][0]=K[b][0]; T[b][1]=K[b][1]; T[b][2]=K[b][2]; }
    FWDQ(T, 4); FWDQ(T, 5);
    z[5] = zdot(S, T);   BWDQ(5);

    #pragma unroll
    for (int b = 0; b < 2; ++b) { T[b][0]=K[b][0]; T[b][1]=K[b][1]; T[b][2]=K[b][2]; }
    FWDQ(T, 4);
    z[4] = zdot(S, T);   BWDQ(4);

    z[3] = zdot(S, K);   BWDQ(3);

    T[0][0]=1.f; T[0][1]=0.f; T[0][2]=0.f; T[1][0]=0.f; T[1][1]=0.f; T[1][2]=0.f;
    FWDQ(T, 0); FWDQ(T, 1); FWDQ(T, 2);
    z[2] = zdot(S, T);   BWDQ(2);

    T[0][0]=1.f; T[0][1]=0.f; T[0][2]=0.f; T[1][0]=0.f; T[1][1]=0.f; T[1][2]=0.f;
    FWDQ(T, 0); FWDQ(T, 1);
    z[1] = zdot(S, T);   BWDQ(1);

    T[0][0]=1.f; T[0][1]=0.f; T[0][2]=0.f; T[1][0]=0.f; T[1][1]=0.f; T[1][2]=0.f;
    FWDQ(T, 0);
    z[0] = zdot(S, T);

#undef FWDQ
#undef BWDQ

    // one representative lane per sample stores (lanes 0-3,16-19,32-35,48-51)
    if ((lane & 12) == 0) {
        float4* o = reinterpret_cast<float4*>(out + (size_t)samp * 8);
        o[0] = make_float4(z[0], z[1], z[2], z[3]);
        o[1] = make_float4(z[4], z[5], z[6], z[7]);
    }
}

extern "C" void kernel_launch(void* const* d_in, const int* in_sizes, int n_in,
                              void* d_out, int out_size, void* d_ws, size_t ws_size,
                              hipStream_t stream) {
    const float* x   = (const float*)d_in[0];
    const float* W   = (const float*)d_in[1];
    const float* sc  = (const float*)d_in[2];
    const float* wt  = (const float*)d_in[3];
    float* o         = (float*)d_out;

    const int batch  = in_sizes[0] / 768;     // 65536
    const int blocks = batch / 64;            // 64 samples per block
    pqc_kernel<<<dim3(blocks), dim3(256), 0, stream>>>(x, W, sc, wt, o);
}

// Round 6
// 51.890 us; speedup vs baseline: 1.3678x; 1.0175x over previous
//
#include <hip/hip_runtime.h>

// PQC: h = tanh(x @ W^T) * scale; 8-qubit circuit via exact transfer-matrix
// contraction (CNOT staircase => MPS bond dim 2; symmetry-reduced 2x3 state).
// R6 = R2's proven GEMM schedule (unroll 2, W via L1, per-p x loads) +
// no-LDS/no-barrier all-lane circuit + fully coalesced float2 stores.
// Row map: lane group s4 owns rows s4*4..s4*4+3 so lane selects sample lane>>2.

__device__ __forceinline__ float fast_tanh(float v) {
    float e = __expf(2.0f * v);
    return 1.0f - 2.0f / (e + 1.0f);   // exact at +/-inf overflow
}

// forward site step: data/layer0-RY conjugation M(A,B,1-A), then layer1-RY+CNOT mix
__device__ __forceinline__ void fwd_step(float (&L)[2][3], float A, float B,
                                         float c2, float cs) {
    float u[2][3];
    #pragma unroll
    for (int b = 0; b < 2; ++b) {
        const float v0 = L[b][0], v1 = L[b][1], v2 = L[b][2];
        const float d  = v0 - v2;
        const float B2 = B + B;
        u[b][0] = fmaf(A, d, fmaf(B2, v1, v2));      // A v0 + 2B v1 + (1-A) v2
        u[b][1] = fmaf(B, v0 + v2, v1);              // B v0 + v1 + B v2
        u[b][2] = fmaf(-A, d, fmaf(B2, v1, v0));     // (1-A) v0 + 2B v1 + A v2
    }
    const float d0 = u[0][0] - u[1][0];
    L[0][0] = fmaf(c2, d0, u[1][0]);
    L[1][0] = fmaf(-c2, d0, u[0][0]);
    const float m = cs * (u[1][1] - u[0][1]);
    L[0][1] = m;  L[1][1] = -m;
    const float d2 = u[1][2] - u[0][2];
    L[0][2] = fmaf(c2, d2, u[0][2]);
    L[1][2] = fmaf(-c2, d2, u[1][2]);
}

// backward site step: mix first, then M (adjoint under (1,2,1) weighting)
__device__ __forceinline__ void bwd_step(float (&S)[2][3], float A, float B,
                                         float c2, float cs) {
    float u[2][3];
    const float d0 = S[0][0] - S[1][0];
    u[0][0] = fmaf(c2, d0, S[1][0]);
    u[1][0] = fmaf(-c2, d0, S[0][0]);
    const float m = cs * (S[1][1] - S[0][1]);
    u[0][1] = m;  u[1][1] = -m;
    const float d2 = S[1][2] - S[0][2];
    u[0][2] = fmaf(c2, d2, S[0][2]);
    u[1][2] = fmaf(-c2, d2, S[1][2]);
    #pragma unroll
    for (int b = 0; b < 2; ++b) {
        const float v0 = u[b][0], v1 = u[b][1], v2 = u[b][2];
        const float d  = v0 - v2;
        const float B2 = B + B;
        S[b][0] = fmaf(A, d, fmaf(B2, v1, v2));
        S[b][1] = fmaf(B, v0 + v2, v1);
        S[b][2] = fmaf(-A, d, fmaf(B2, v1, v0));
    }
}

__device__ __forceinline__ float zdot(const float (&S)[2][3], const float (&L)[2][3]) {
    return (S[0][0]*L[0][0] + 2.f*S[0][1]*L[0][1] + S[0][2]*L[0][2])
         - (S[1][0]*L[1][0] + 2.f*S[1][1]*L[1][1] + S[1][2]*L[1][2]);
}

__global__ __launch_bounds__(256, 3)
void pqc_kernel(const float* __restrict__ x,
                const float* __restrict__ Wp,
                const float* __restrict__ scalep,
                const float* __restrict__ wts,
                float* __restrict__ out)
{
    const int tid   = threadIdx.x;
    const int lane  = tid & 63;
    const int wave  = tid >> 6;
    const int rbase = blockIdx.x * 64 + wave * 16;

    const int s4  = lane >> 4;      // row group: owns rows s4*4 .. s4*4+3
    const int c16 = lane & 15;      // column group

    // ---------------- projection: 16 samples per wave (R2 schedule) ----------
    const float* xrow = x + (size_t)(rbase + s4 * 4) * 768 + c16 * 4;

    float acc[4][8];
    #pragma unroll
    for (int p = 0; p < 4; ++p)
        #pragma unroll
        for (int q = 0; q < 8; ++q) acc[p][q] = 0.0f;

    #pragma unroll 2
    for (int j = 0; j < 12; ++j) {
        float4 wv[8];
        #pragma unroll
        for (int q = 0; q < 8; ++q)
            wv[q] = *reinterpret_cast<const float4*>(Wp + q * 768 + j * 64 + c16 * 4);
        #pragma unroll
        for (int p = 0; p < 4; ++p) {
            const float4 xv = *reinterpret_cast<const float4*>(xrow + p * 768 + j * 64);
            #pragma unroll
            for (int q = 0; q < 8; ++q) {
                acc[p][q] = fmaf(xv.x, wv[q].x, acc[p][q]);
                acc[p][q] = fmaf(xv.y, wv[q].y, acc[p][q]);
                acc[p][q] = fmaf(xv.z, wv[q].z, acc[p][q]);
                acc[p][q] = fmaf(xv.w, wv[q].w, acc[p][q]);
            }
        }
    }

    // butterfly reduce over the 16 column lanes (bits 0..3)
    #pragma unroll
    for (int m = 1; m <= 8; m <<= 1)
        #pragma unroll
        for (int p = 0; p < 4; ++p)
            #pragma unroll
            for (int q = 0; q < 8; ++q)
                acc[p][q] += __shfl_xor(acc[p][q], m, 64);

    // lane selects sample lane>>2 (its row group's p = (lane>>2)&3); 4x redundant
    const bool sb0 = (lane & 4) != 0;
    const bool sb1 = (lane & 8) != 0;
    float h[8];
    #pragma unroll
    for (int q = 0; q < 8; ++q) {
        const float v01 = sb0 ? acc[1][q] : acc[0][q];
        const float v23 = sb0 ? acc[3][q] : acc[2][q];
        h[q] = sb1 ? v23 : v01;
    }

    // ---------------- per-site tables ----------------
    const float scl = scalep[0];
    float Aq[8], Bq[8], c2q[8], csq[8];
    #pragma unroll
    for (int q = 0; q < 8; ++q) {
        float ang = fast_tanh(h[q]) * scl + wts[q];   // fold layer-0 weight RY
        float s, c;
        __sincosf(0.5f * ang, &s, &c);
        Aq[q] = c * c;  Bq[q] = c * s;
        float sw, cw;
        __sincosf(0.5f * wts[8 + q], &sw, &cw);
        c2q[q] = cw * cw;  csq[q] = cw * sw;
    }

#define FWDQ(T, qq) fwd_step(T, Aq[qq], Bq[qq], c2q[qq], csq[qq])
#define BWDQ(qq)    bwd_step(S, Aq[qq], Bq[qq], c2q[qq], csq[qq])

    // ---------------- forward sweep with midpoint checkpoint ----------------
    float L[2][3] = {{1.f, 0.f, 0.f}, {0.f, 0.f, 0.f}};
    float K[2][3];                                    // checkpoint L_4
    #pragma unroll
    for (int q = 0; q < 8; ++q) {
        FWDQ(L, q);
        if (q == 3) {
            #pragma unroll
            for (int b = 0; b < 2; ++b)
                #pragma unroll
                for (int t = 0; t < 3; ++t) K[b][t] = L[b][t];
        }
    }

    // ---------------- backward sweep with recompute ----------------
    float S[2][3] = {{1.f, 1.f, 1.f}, {1.f, 1.f, 1.f}};
    float z[8];
    float T[2][3];

    z[7] = zdot(S, L);   BWDQ(7);

    #pragma unroll
    for (int b = 0; b < 2; ++b) { T[b][0]=K[b][0]; T[b][1]=K[b][1]; T[b][2]=K[b][2]; }
    FWDQ(T, 4); FWDQ(T, 5); FWDQ(T, 6);
    z[6] = zdot(S, T);   BWDQ(6);

    #pragma unroll
    for (int b = 0; b < 2; ++b) { T[b][0]=K[b][0]; T[b][1]=K[b][1]; T[b][2]=K[b][2]; }
    FWDQ(T, 4); FWDQ(T, 5);
    z[5] = zdot(S, T);   BWDQ(5);

    #pragma unroll
    for (int b = 0; b < 2; ++b) { T[b][0]=K[b][0]; T[b][1]=K[b][1]; T[b][2]=K[b][2]; }
    FWDQ(T, 4);
    z[4] = zdot(S, T);   BWDQ(4);

    z[3] = zdot(S, K);   BWDQ(3);

    T[0][0]=1.f; T[0][1]=0.f; T[0][2]=0.f; T[1][0]=0.f; T[1][1]=0.f; T[1][2]=0.f;
    FWDQ(T, 0); FWDQ(T, 1); FWDQ(T, 2);
    z[2] = zdot(S, T);   BWDQ(2);

    T[0][0]=1.f; T[0][1]=0.f; T[0][2]=0.f; T[1][0]=0.f; T[1][1]=0.f; T[1][2]=0.f;
    FWDQ(T, 0); FWDQ(T, 1);
    z[1] = zdot(S, T);   BWDQ(1);

    T[0][0]=1.f; T[0][1]=0.f; T[0][2]=0.f; T[1][0]=0.f; T[1][1]=0.f; T[1][2]=0.f;
    FWDQ(T, 0);
    z[0] = zdot(S, T);

#undef FWDQ
#undef BWDQ

    // coalesced store: lane writes float2 {z[2k], z[2k+1]}, k = lane&3,
    // for sample rbase + (lane>>2)  =>  out + rbase*8 + lane*2
    const bool q0 = (lane & 1) != 0;
    const bool q1 = (lane & 2) != 0;
    const float lo01 = q0 ? z[2] : z[0];
    const float lo23 = q0 ? z[6] : z[4];
    const float hi01 = q0 ? z[3] : z[1];
    const float hi23 = q0 ? z[7] : z[5];
    const float lo = q1 ? lo23 : lo01;
    const float hi = q1 ? hi23 : hi01;
    *reinterpret_cast<float2*>(out + (size_t)rbase * 8 + lane * 2) = make_float2(lo, hi);
}

extern "C" void kernel_launch(void* const* d_in, const int* in_sizes, int n_in,
                              void* d_out, int out_size, void* d_ws, size_t ws_size,
                              hipStream_t stream) {
    const float* x   = (const float*)d_in[0];
    const float* W   = (const float*)d_in[1];
    const float* sc  = (const float*)d_in[2];
    const float* wt  = (const float*)d_in[3];
    float* o         = (float*)d_out;

    const int batch  = in_sizes[0] / 768;     // 65536
    const int blocks = batch / 64;            // 64 samples per block
    pqc_kernel<<<dim3(blocks), dim3(256), 0, stream>>>(x, W, sc, wt, o);
}

// Round 7
// 43.305 us; speedup vs baseline: 1.6389x; 1.1982x over previous
//
#include <hip/hip_runtime.h>

// PQC: h = tanh(x @ W^T) * scale; 8-qubit circuit via exact transfer-matrix
// contraction (CNOT staircase = prefix-XOR => MPS bond dim 2 per staircase;
// <Z_i> = 1D chain contraction with 2x2x2 state, symmetry-reduced to 2x3).
// Per-sample cost ~700 thread-local FMAs, no cross-lane ops at all.
// R7 = exact reproduction of the R2 43.6us kernel (arbitrating structure vs noise).

__device__ __forceinline__ float fast_tanh(float v) {
    float e = __expf(2.0f * v);
    return 1.0f - 2.0f / (e + 1.0f);   // exact at +/-inf overflow
}

__global__ __launch_bounds__(256, 3)
void pqc_kernel(const float* __restrict__ x,
                const float* __restrict__ Wp,
                const float* __restrict__ scalep,
                const float* __restrict__ wts,
                float* __restrict__ out)
{
    __shared__ float hb[64][8];   // per-block projection results (pre-tanh)

    const int tid  = threadIdx.x;
    const int lane = tid & 63;
    const int wave = tid >> 6;            // 0..3
    const int b0   = blockIdx.x * 64;

    const int s4  = lane >> 4;            // 0..3  sample sub-group
    const int c16 = lane & 15;            // 0..15 column group

    // ---------------- projection phase: this wave's 16 samples ----------------
    const int rbase = b0 + wave * 16;
    float acc[4][8];
    #pragma unroll
    for (int p = 0; p < 4; ++p)
        #pragma unroll
        for (int q = 0; q < 8; ++q) acc[p][q] = 0.0f;

    #pragma unroll 2
    for (int j = 0; j < 12; ++j) {
        const int col4 = j * 16 + c16;    // float4 index within a 768-float row
        float4 wv[8];
        #pragma unroll
        for (int q = 0; q < 8; ++q)
            wv[q] = *reinterpret_cast<const float4*>(Wp + q * 768 + col4 * 4);
        #pragma unroll
        for (int p = 0; p < 4; ++p) {
            const float4 xv = *reinterpret_cast<const float4*>(
                x + (size_t)(rbase + p * 4 + s4) * 768 + col4 * 4);
            #pragma unroll
            for (int q = 0; q < 8; ++q) {
                acc[p][q] = fmaf(xv.x, wv[q].x, acc[p][q]);
                acc[p][q] = fmaf(xv.y, wv[q].y, acc[p][q]);
                acc[p][q] = fmaf(xv.z, wv[q].z, acc[p][q]);
                acc[p][q] = fmaf(xv.w, wv[q].w, acc[p][q]);
            }
        }
    }
    // reduce over the 16 column lanes
    #pragma unroll
    for (int m = 1; m <= 8; m <<= 1)
        #pragma unroll
        for (int p = 0; p < 4; ++p)
            #pragma unroll
            for (int q = 0; q < 8; ++q)
                acc[p][q] += __shfl_xor(acc[p][q], m, 64);

    if (c16 == 0) {
        #pragma unroll
        for (int p = 0; p < 4; ++p) {
            const int srow = wave * 16 + p * 4 + s4;
            #pragma unroll
            for (int q = 0; q < 8; ++q) hb[srow][q] = acc[p][q];
        }
    }
    __syncthreads();

    // ---------------- circuit phase: transfer-matrix, one sample per thread ----
    // Active: lanes 0..15 of each wave -> 64 samples per block, one per thread.
    if (lane < 16) {
        const int sl   = wave * 16 + lane;     // local sample 0..63
        const int samp = b0 + sl;
        const float scl = scalep[0];

        // per-sample single-qubit input amplitudes: f0=cos(phi/2), f1=sin(phi/2)
        // phi folds the data RY and the layer-0 weight RY (both pre-entangler).
        float f0[8], f1[8];
        #pragma unroll
        for (int q = 0; q < 8; ++q) {
            float ang = fast_tanh(hb[sl][q]) * scl + wts[q];
            __sincosf(0.5f * ang, &f1[q], &f0[q]);
        }
        // layer-1 RY params (uniform): G-tables c^2, s^2, c*s
        float c2[8], s2[8], cs[8];
        #pragma unroll
        for (int q = 0; q < 8; ++q) {
            float sw, cw;
            __sincosf(0.5f * wts[8 + q], &sw, &cw);
            c2[q] = cw * cw; s2[q] = sw * sw; cs[q] = cw * sw;
        }

        // state vector over (b, sym(beta,beta~)): [2][3], t: 0=(00),1=(01/10),2=(11)
        // prefix sweep: Lp[q] = L^(q); Lp[0] = e_{b=0,t=0}
        float Lp[9][2][3];
        Lp[0][0][0] = 1.f; Lp[0][0][1] = 0.f; Lp[0][0][2] = 0.f;
        Lp[0][1][0] = 0.f; Lp[0][1][1] = 0.f; Lp[0][1][2] = 0.f;

        #pragma unroll
        for (int q = 0; q < 8; ++q) {
            const float A = f0[q] * f0[q];
            const float B = f0[q] * f1[q];
            const float C = f1[q] * f1[q];
            float u[2][3];
            #pragma unroll
            for (int b = 0; b < 2; ++b) {
                const float v0 = Lp[q][b][0], v1 = Lp[q][b][1], v2 = Lp[q][b][2];
                u[b][0] = A * v0 + 2.f * B * v1 + C * v2;
                u[b][1] = B * v0 + (A + C) * v1 + B * v2;
                u[b][2] = C * v0 + 2.f * B * v1 + A * v2;
            }
            Lp[q+1][0][0] = c2[q] * u[0][0] + s2[q] * u[1][0];
            Lp[q+1][1][0] = s2[q] * u[0][0] + c2[q] * u[1][0];
            const float m = cs[q] * (u[1][1] - u[0][1]);
            Lp[q+1][0][1] = m;
            Lp[q+1][1][1] = -m;
            Lp[q+1][0][2] = s2[q] * u[0][2] + c2[q] * u[1][2];
            Lp[q+1][1][2] = c2[q] * u[0][2] + s2[q] * u[1][2];
        }

        // suffix sweep + signed dots: z_i = <S^(i+1), (+/- on b) L^(i+1)>
        float S[2][3] = {{1.f, 1.f, 1.f}, {1.f, 1.f, 1.f}};
        float z[8];
        #pragma unroll
        for (int i = 7; i >= 0; --i) {
            z[i] = (S[0][0] * Lp[i+1][0][0] + 2.f * S[0][1] * Lp[i+1][0][1] + S[0][2] * Lp[i+1][0][2])
                 - (S[1][0] * Lp[i+1][1][0] + 2.f * S[1][1] * Lp[i+1][1][1] + S[1][2] * Lp[i+1][1][2]);
            if (i > 0) {
                float u[2][3];
                u[0][0] = c2[i] * S[0][0] + s2[i] * S[1][0];
                u[1][0] = s2[i] * S[0][0] + c2[i] * S[1][0];
                const float m = cs[i] * (S[1][1] - S[0][1]);
                u[0][1] = m; u[1][1] = -m;
                u[0][2] = s2[i] * S[0][2] + c2[i] * S[1][2];
                u[1][2] = c2[i] * S[0][2] + s2[i] * S[1][2];
                const float A = f0[i] * f0[i];
                const float B = f0[i] * f1[i];
                const float C = f1[i] * f1[i];
                #pragma unroll
                for (int b = 0; b < 2; ++b) {
                    const float u0 = u[b][0], u1 = u[b][1], u2 = u[b][2];
                    S[b][0] = A * u0 + 2.f * B * u1 + C * u2;
                    S[b][1] = B * u0 + (A + C) * u1 + B * u2;
                    S[b][2] = C * u0 + 2.f * B * u1 + A * u2;
                }
            }
        }

        float4* o = reinterpret_cast<float4*>(out + (size_t)samp * 8);
        o[0] = make_float4(z[0], z[1], z[2], z[3]);
        o[1] = make_float4(z[4], z[5], z[6], z[7]);
    }
}

extern "C" void kernel_launch(void* const* d_in, const int* in_sizes, int n_in,
                              void* d_out, int out_size, void* d_ws, size_t ws_size,
                              hipStream_t stream) {
    const float* x   = (const float*)d_in[0];
    const float* W   = (const float*)d_in[1];
    const float* sc  = (const float*)d_in[2];
    const float* wt  = (const float*)d_in[3];
    float* o         = (float*)d_out;

    const int batch  = in_sizes[0] / 768;     // 65536
    const int blocks = batch / 64;            // 64 samples per block
    pqc_kernel<<<dim3(blocks), dim3(256), 0, stream>>>(x, W, sc, wt, o);
}